// Round 7
// baseline (612.413 us; speedup 1.0000x reference)
//
#include <hip/hip_runtime.h>
#include <math.h>

#define B_SZ 4
#define IN_F 32
#define H1_F 32
#define H2_F 30
#define TPW 16   // tiles per wave (multiple of 4)

typedef unsigned int uint;
typedef unsigned short ushort;
typedef __attribute__((ext_vector_type(8))) short bf16x8;
typedef __attribute__((ext_vector_type(4))) float f32x4;

__device__ __forceinline__ float fastrcp(float x) {
#if __has_builtin(__builtin_amdgcn_rcpf)
    return __builtin_amdgcn_rcpf(x);
#else
    return 1.f / x;
#endif
}
__device__ __forceinline__ float sigmoidf_(float x) {
    return fastrcp(1.f + __expf(-x));
}
__device__ __forceinline__ ushort f2bf(float f) {
    uint u = __float_as_uint(f);
    return (ushort)((u + 0x7FFFu + ((u >> 16) & 1u)) >> 16);  // RNE
}
__device__ __forceinline__ float bf2f(ushort v) { return __uint_as_float(((uint)v) << 16); }
__device__ __forceinline__ uint pk2(float a, float b) {
    return (uint)f2bf(a) | ((uint)f2bf(b) << 16);
}

union Frag { bf16x8 v; ushort us[8]; uint u[4]; };

// ---------------------------------------------------------------------------
// fused stats (mean/sumsq of ea) + degree histogram (tgt+src combined)
// ---------------------------------------------------------------------------
__global__ void __launch_bounds__(256) stats_hist_kernel(
    const float* __restrict__ ea, const int* __restrict__ ei,
    float* __restrict__ sums, int* __restrict__ cnt, int E, int N) {
    int e = blockIdx.x * 256 + threadIdx.x;
    float a = (e < E) ? ea[e] : 0.f;
    if (e < E) {
        atomicAdd(&cnt[ei[E + e]], 1);
        atomicAdd(&cnt[ei[e]], 1);
    }
    float v = a, v2 = a * a;
    for (int off = 32; off > 0; off >>= 1) {
        v  += __shfl_down(v, off);
        v2 += __shfl_down(v2, off);
    }
    __shared__ float s1[4], s2[4];
    int wid = threadIdx.x >> 6, lane = threadIdx.x & 63;
    if (lane == 0) { s1[wid] = v; s2[wid] = v2; }
    __syncthreads();
    if (threadIdx.x == 0) {
        unsafeAtomicAdd(&sums[0], s1[0] + s1[1] + s1[2] + s1[3]);
        unsafeAtomicAdd(&sums[1], s2[0] + s2[1] + s2[2] + s2[3]);
    }
}

// ---------------------------------------------------------------------------
// x f32 -> bf16 conversion (8 elems/thread)
// ---------------------------------------------------------------------------
__global__ void __launch_bounds__(256) xcvt_kernel(const float* __restrict__ x,
                                                   ushort* __restrict__ xb,
                                                   long long n8) {
    long long i = (long long)blockIdx.x * 256 + threadIdx.x;
    if (i >= n8) return;
    const float4* p = (const float4*)(x + i * 8);
    float4 v0 = p[0], v1 = p[1];
    uint4 o;
    o.x = pk2(v0.x, v0.y); o.y = pk2(v0.z, v0.w);
    o.z = pk2(v1.x, v1.y); o.w = pk2(v1.z, v1.w);
    *(uint4*)(xb + i * 8) = o;
}

// ---------------------------------------------------------------------------
// 3-phase multi-block exclusive scan (1024 elems/block)
// ---------------------------------------------------------------------------
__global__ void __launch_bounds__(256) scan1_kernel(const int* __restrict__ cnt,
                                                    int* __restrict__ offs,
                                                    int* __restrict__ bsum, int n) {
    __shared__ int wtot[4];
    int base = blockIdx.x * 1024 + threadIdx.x * 4;
    int4 v = {0, 0, 0, 0};
    if (base + 3 < n) v = *(const int4*)(cnt + base);
    else {
        if (base < n)     v.x = cnt[base];
        if (base + 1 < n) v.y = cnt[base + 1];
        if (base + 2 < n) v.z = cnt[base + 2];
        if (base + 3 < n) v.w = cnt[base + 3];
    }
    int s = v.x + v.y + v.z + v.w;
    int incl = s;
    int lane = threadIdx.x & 63;
    for (int d = 1; d < 64; d <<= 1) {
        int t = __shfl_up(incl, d);
        if (lane >= d) incl += t;
    }
    int wid = threadIdx.x >> 6;
    if (lane == 63) wtot[wid] = incl;
    __syncthreads();
    int woff = 0, tot = 0;
#pragma unroll
    for (int w = 0; w < 4; w++) {
        int t = wtot[w];
        if (w < wid) woff += t;
        tot += t;
    }
    int excl = woff + incl - s;
    int4 o;
    o.x = excl; o.y = excl + v.x; o.z = o.y + v.y; o.w = o.z + v.z;
    if (base + 3 < n) *(int4*)(offs + base) = o;
    else {
        if (base < n)     offs[base] = o.x;
        if (base + 1 < n) offs[base + 1] = o.y;
        if (base + 2 < n) offs[base + 2] = o.z;
        if (base + 3 < n) offs[base + 3] = o.w;
    }
    if (threadIdx.x == 0) bsum[blockIdx.x] = tot;
}

__global__ void scan2_kernel(int* __restrict__ bsum, int* __restrict__ offs,
                             int nb, int n) {
    int lane = threadIdx.x;
    if (nb <= 64) {
        int v = (lane < nb) ? bsum[lane] : 0;
        int incl = v;
        for (int d = 1; d < 64; d <<= 1) {
            int t = __shfl_up(incl, d);
            if (lane >= d) incl += t;
        }
        if (lane < nb) bsum[lane] = incl - v;
        if (lane == 63) offs[n] = incl;
    } else if (lane == 0) {
        int run = 0;
        for (int i = 0; i < nb; i++) { int t = bsum[i]; bsum[i] = run; run += t; }
        offs[n] = run;
    }
}

__global__ void __launch_bounds__(256) scan3_kernel(int* __restrict__ offs,
                                                    int* __restrict__ cursor,
                                                    const int* __restrict__ bsum, int n) {
    int base = blockIdx.x * 1024 + threadIdx.x * 4;
    int add = bsum[blockIdx.x];
    if (base + 3 < n) {
        int4 v = *(const int4*)(offs + base);
        v.x += add; v.y += add; v.z += add; v.w += add;
        *(int4*)(offs + base) = v;
        *(int4*)(cursor + base) = v;
    } else {
        for (int k = 0; k < 4; k++) {
            int i = base + k;
            if (i < n) { int v = offs[i] + add; offs[i] = v; cursor[i] = v; }
        }
    }
}

// ---------------------------------------------------------------------------
// Edge MLP (operand-swapped MFMA), two-batch pass, +/-h direct into CSR slots.
// Tile = 8 edges x 2 batches = 16 rows; row n16 = el*2 + bl.
// HSTEP=16: padded 128-B slots, FULLY written (no RMW); HSTEP=15: packed 120 B.
// Cursor atomics issued per GROUP of 4 tiles (all 64 lanes, 1 each), one group
// ahead. Data (ei/ea/xb) prefetched with 3-buffer rotation (~2.7 tiles ahead).
// ---------------------------------------------------------------------------
template<int HSTEP>
__global__ void __launch_bounds__(256) edge_mlp_slot(
    const ushort* __restrict__ xb,
    const int* __restrict__ ei, const float* __restrict__ ea,
    const float* __restrict__ W1, const float* __restrict__ b1,
    const float* __restrict__ W2, const float* __restrict__ b2,
    const float* __restrict__ sums, int* __restrict__ cursor,
    ushort* __restrict__ h, int E, int N, int tiles, int boff) {
    __shared__ ushort __attribute__((aligned(16))) hbuf[4][16 * 40];
    int w = threadIdx.x >> 6;
    int lane = threadIdx.x & 63;
    int n16 = lane & 15;
    int q = lane >> 4;

    // weight fragments as operand A (= W^T)
    Frag w1f[2][2];
#pragma unroll
    for (int t = 0; t < 2; t++)
#pragma unroll
        for (int s = 0; s < 2; s++)
#pragma unroll
            for (int j = 0; j < 4; j++) {
                int k0 = 32 * s + q * 8 + 2 * j;
                w1f[t][s].u[j] = pk2(W1[(size_t)k0 * 32 + 16 * t + n16],
                                     W1[(size_t)(k0 + 1) * 32 + 16 * t + n16]);
            }
    Frag w2f[2];
#pragma unroll
    for (int t = 0; t < 2; t++) {
        int m = 16 * t + n16;
#pragma unroll
        for (int j = 0; j < 4; j++) {
            int k0 = q * 8 + 2 * j;
            float a = (m < H2_F) ? W2[(size_t)k0 * H2_F + m] : 0.f;
            float d = (m < H2_F) ? W2[(size_t)(k0 + 1) * H2_F + m] : 0.f;
            w2f[t].u[j] = pk2(a, d);
        }
    }
    float b1q[2][4], w1Lq[2][4], b2q[2][4];
#pragma unroll
    for (int t = 0; t < 2; t++)
#pragma unroll
        for (int r = 0; r < 4; r++) {
            int col = 16 * t + q * 4 + r;
            b1q[t][r]  = b1[col];
            w1Lq[t][r] = W1[(size_t)64 * 32 + col];
            b2q[t][r]  = (col < H2_F) ? b2[col] : 0.f;
        }

    float mean = sums[0] / (float)E;
    float var = (sums[1] - (float)E * mean * mean) / (float)(E - 1);
    float istd = rsqrtf(var);

    int el = n16 >> 1;            // row's edge offset within tile
    int bl = n16 & 1;             // row's batch-local
    int b  = bl + boff;
    int side = n16 & 1;           // atomic role: 0=tgt(+), 1=src(-)
    int gw = blockIdx.x * 4 + w;
    int tile0 = gw * TPW;
    if (tile0 >= tiles) return;

    // ---- group-of-4 cursor atomics: lane = tq*16 + (el*2+side) ----
    auto issue4 = [&](int gt0) -> int {
        int tt = gt0 + q;                  // tile within group = quad
        int eAt = tt * 8 + el;
        int slotv = 0;
        if (tt < tiles && eAt < E) {
            int node = side ? ei[eAt] : ei[E + eAt];
            slotv = atomicAdd(&cursor[node], 1);
        }
        return slotv;
    };

    // ---- 3-buffer rotating data prefetch ----
    Frag a0b[3], a1b[3];
    float eavb[3];
    bool vrb[3];
    auto loadTile = [&](int tt, int sl) {
        Frag x0, x1;
        x0.u[0] = x0.u[1] = x0.u[2] = x0.u[3] = 0; x1 = x0;
        float ev = 0.f; bool v = false;
        if (tt < tiles) {
            int eA = tt * 8 + el;
            v = eA < E;
            int c = v ? eA : E - 1;
            int s_ = ei[c], t_ = ei[E + c];
            ev = (ea[c] - mean) * istd;
            *(uint4*)&x0.u[0] = *(const uint4*)(xb + ((size_t)b * N + s_) * IN_F + q * 8);
            *(uint4*)&x1.u[0] = *(const uint4*)(xb + ((size_t)b * N + t_) * IN_F + q * 8);
        }
        a0b[sl] = x0; a1b[sl] = x1; eavb[sl] = ev; vrb[sl] = v;
    };

    int slotCur = issue4(tile0);
    int slotNxt = 0;
    loadTile(tile0, 0);
    loadTile(tile0 + 1, 1);
    loadTile(tile0 + 2, 2);

    for (int tix = 0; tix < TPW; ++tix) {
        int tile = tile0 + tix;
        if (tile >= tiles) break;
        int p = tix & 3;
        if (p == 0 && tix + 4 < TPW) slotNxt = issue4(tile0 + tix + 4);
        int cur = tix % 3;

        // layer 1 from buffers
        float eav = eavb[cur];
        bool vrow = vrb[cur];
        f32x4 acc0, acc1;
#pragma unroll
        for (int r = 0; r < 4; r++) {
            acc0[r] = b1q[0][r] + eav * w1Lq[0][r];
            acc1[r] = b1q[1][r] + eav * w1Lq[1][r];
        }
        acc0 = __builtin_amdgcn_mfma_f32_16x16x32_bf16(w1f[0][0].v, a0b[cur].v, acc0, 0, 0, 0);
        acc0 = __builtin_amdgcn_mfma_f32_16x16x32_bf16(w1f[0][1].v, a1b[cur].v, acc0, 0, 0, 0);
        acc1 = __builtin_amdgcn_mfma_f32_16x16x32_bf16(w1f[1][0].v, a0b[cur].v, acc1, 0, 0, 0);
        acc1 = __builtin_amdgcn_mfma_f32_16x16x32_bf16(w1f[1][1].v, a1b[cur].v, acc1, 0, 0, 0);

        // buffers for this slot are dead now -> prefetch tile tix+3 into them
        if (tix + 3 < TPW) loadTile(tile0 + tix + 3, cur);

        uint u0 = pk2(sigmoidf_(acc0[0]), sigmoidf_(acc0[1]));
        uint u1 = pk2(sigmoidf_(acc0[2]), sigmoidf_(acc0[3]));
        uint u2 = pk2(sigmoidf_(acc1[0]), sigmoidf_(acc1[1]));
        uint u3 = pk2(sigmoidf_(acc1[2]), sigmoidf_(acc1[3]));
        uint2 p01 = {u0, u1}, p23 = {u2, u3};
        *(uint2*)&hbuf[w][n16 * 40 + q * 4]      = p01;
        *(uint2*)&hbuf[w][n16 * 40 + 16 + q * 4] = p23;

        Frag ha;
        *(uint4*)&ha.u[0] = *(const uint4*)&hbuf[w][n16 * 40 + q * 8];

        f32x4 c0, c1;
#pragma unroll
        for (int r = 0; r < 4; r++) { c0[r] = b2q[0][r]; c1[r] = b2q[1][r]; }
        c0 = __builtin_amdgcn_mfma_f32_16x16x32_bf16(w2f[0].v, ha.v, c0, 0, 0, 0);
        c1 = __builtin_amdgcn_mfma_f32_16x16x32_bf16(w2f[1].v, ha.v, c1, 0, 0, 0);

        uint g0 = pk2(sigmoidf_(c0[0]), sigmoidf_(c0[1]));
        uint g1 = pk2(sigmoidf_(c0[2]), sigmoidf_(c0[3]));
        uint g2 = pk2(sigmoidf_(c1[0]), sigmoidf_(c1[1]));
        uint g3 = pk2(sigmoidf_(c1[2]), sigmoidf_(c1[3]));  // q==3 -> cols 30,31 (pad)

        int slot_t = __shfl(slotCur, p * 16 + el * 2);
        int slot_s = __shfl(slotCur, p * 16 + el * 2 + 1);
        if (vrow) {
            const uint SM = 0x80008000u;
            if (HSTEP == 16) {
                // fully-written 128-B slots, aligned uint2 stores
                uint2 s01 = {u0, u1};  (void)s01;
                uint2 t01 = {g0, g1}, t23 = {g2, g3};
                uint* bt = (uint*)h + (size_t)slot_t * 32 + bl * 16;
                *(uint2*)(bt + q * 2)     = t01;
                *(uint2*)(bt + 8 + q * 2) = t23;
                uint2 n01 = {g0 ^ SM, g1 ^ SM}, n23 = {g2 ^ SM, g3 ^ SM};
                uint* bs = (uint*)h + (size_t)slot_s * 32 + bl * 16;
                *(uint2*)(bs + q * 2)     = n01;
                *(uint2*)(bs + 8 + q * 2) = n23;
            } else {
                uint* bt = (uint*)h + (size_t)slot_t * 30 + bl * 15;
                bt[q * 2]     = g0;
                bt[q * 2 + 1] = g1;
                bt[8 + q * 2] = g2;
                if (q < 3) bt[8 + q * 2 + 1] = g3;
                uint* bs = (uint*)h + (size_t)slot_s * 30 + bl * 15;
                bs[q * 2]     = g0 ^ SM;
                bs[q * 2 + 1] = g1 ^ SM;
                bs[8 + q * 2] = g2 ^ SM;
                if (q < 3) bs[8 + q * 2 + 1] = g3 ^ SM;
            }
        }
        if (p == 3) slotCur = slotNxt;
    }
}

// ---------------------------------------------------------------------------
// Gather over CONTIGUOUS slots (signs baked in), fused W3 epilogue.
// Lane 30 restores cursor[n] = offs[n] for the next pass (free).
// ---------------------------------------------------------------------------
__global__ void __launch_bounds__(256) gather_slot(
    const ushort* __restrict__ h, const int* __restrict__ offs,
    int* __restrict__ cursor,
    const float* __restrict__ W3, const float* __restrict__ b3,
    float* __restrict__ out, int N, int boff, int hstep) {
    __shared__ float sW3[H2_F * 32];
    __shared__ float sb3[32];
    __shared__ float sacc[4][2][H2_F];
    for (int i = threadIdx.x; i < H2_F * 32; i += 256) sW3[i] = W3[i];
    if (threadIdx.x < 32) sb3[threadIdx.x] = b3[threadIdx.x];
    __syncthreads();

    int w = threadIdx.x >> 6, lane = threadIdx.x & 63;
    int n = blockIdx.x * 4 + w;
    if (n >= N) return;

    int s = offs[n], e = offs[n + 1];
    if (lane == 30) cursor[n] = s;
    int sstr = 2 * hstep;
    if (lane < 30) {
        int bl = lane / 15, jp = lane % 15;
        const uint* p = (const uint*)h + (size_t)s * sstr + bl * hstep + jp;
        float a0 = 0.f, a1 = 0.f;
        int cnt = e - s;
        int i = 0;
        for (; i + 4 <= cnt; i += 4) {
            uint d0 = p[0], d1 = p[sstr], d2 = p[2 * sstr], d3 = p[3 * sstr];
            p += 4 * sstr;
            a0 += bf2f((ushort)d0) + bf2f((ushort)d1)
                + bf2f((ushort)d2) + bf2f((ushort)d3);
            a1 += bf2f((ushort)(d0 >> 16)) + bf2f((ushort)(d1 >> 16))
                + bf2f((ushort)(d2 >> 16)) + bf2f((ushort)(d3 >> 16));
        }
        for (; i < cnt; i++) {
            uint d = p[0];
            p += sstr;
            a0 += bf2f((ushort)d);
            a1 += bf2f((ushort)(d >> 16));
        }
        sacc[w][bl][jp * 2]     = a0;
        sacc[w][bl][jp * 2 + 1] = a1;
    }
    // wave-synchronous epilogue: 2 batches x 32 cols = 64 lanes
    int bl = lane >> 5, k = lane & 31;
    float o = sb3[k];
#pragma unroll
    for (int j = 0; j < H2_F; j++) o += sacc[w][bl][j] * sW3[j * 32 + k];
    out[((size_t)(boff + bl) * N + n) * 32 + k] = sigmoidf_(o);
}

// ---------------------------------------------------------------------------
extern "C" void kernel_launch(void* const* d_in, const int* in_sizes, int n_in,
                              void* d_out, int out_size, void* d_ws, size_t ws_size,
                              hipStream_t stream) {
    const float* x  = (const float*)d_in[0];
    const int*   ei = (const int*)d_in[1];
    const float* ea = (const float*)d_in[2];
    const float* W1 = (const float*)d_in[3];
    const float* b1 = (const float*)d_in[4];
    const float* W2 = (const float*)d_in[5];
    const float* b2 = (const float*)d_in[6];
    const float* W3 = (const float*)d_in[7];
    const float* b3 = (const float*)d_in[8];
    float* out = (float*)d_out;

    const int E  = in_sizes[2];
    const int N  = in_sizes[0] / (B_SZ * IN_F);
    const int BN = B_SZ * N;
    const int nb = (N + 1023) / 1024;
    const int tiles = (E + 7) / 8;
    const int waves = (tiles + TPW - 1) / TPW;
    const int eblocks = (waves + 3) / 4;

    char* base = (char*)d_ws;
    size_t misc = 0;
    int* cnt    = (int*)(base + misc); misc += (size_t)N * 4;
    float* sums = (float*)(base + misc); misc += 8;
    int* offs   = (int*)(base + misc); misc += (size_t)(N + 1) * 4;
    int* cursor = (int*)(base + misc); misc += (size_t)N * 4;
    int* bsum   = (int*)(base + misc); misc += 4096;
    misc = (misc + 255) & ~(size_t)255;
    ushort* h   = (ushort*)(base + misc);

    size_t hPad  = (size_t)2 * E * 128;   // 128-B padded slots
    size_t hPack = (size_t)2 * E * 120;   // 120-B packed slots
    size_t xbOffPad  = (misc + hPad  + 255) & ~(size_t)255;
    size_t xbOffPack = (misc + hPack + 255) & ~(size_t)255;
    size_t xbBytes = (size_t)BN * IN_F * 2;
    bool usePad = (ws_size >= xbOffPad + xbBytes);
    size_t xbOff = usePad ? xbOffPad : xbOffPack;
    ushort* xb = (ushort*)(base + xbOff);

    hipMemsetAsync(cnt, 0, (size_t)N * 4 + 8, stream);  // cnt + sums
    stats_hist_kernel<<<(E + 255) / 256, 256, 0, stream>>>(ea, ei, sums, cnt, E, N);
    long long n8 = (long long)BN * IN_F / 8;
    xcvt_kernel<<<(int)((n8 + 255) / 256), 256, 0, stream>>>(x, xb, n8);
    scan1_kernel<<<nb, 256, 0, stream>>>(cnt, offs, bsum, N);
    scan2_kernel<<<1, 64, 0, stream>>>(bsum, offs, nb, N);
    scan3_kernel<<<nb, 256, 0, stream>>>(offs, cursor, bsum, N);

    int gblocks = (N + 3) / 4;
    if (usePad) {
        edge_mlp_slot<16><<<eblocks, 256, 0, stream>>>(xb, ei, ea, W1, b1, W2, b2,
                                                       sums, cursor, h, E, N, tiles, 0);
        gather_slot<<<gblocks, 256, 0, stream>>>(h, offs, cursor, W3, b3, out, N, 0, 16);
        edge_mlp_slot<16><<<eblocks, 256, 0, stream>>>(xb, ei, ea, W1, b1, W2, b2,
                                                       sums, cursor, h, E, N, tiles, 2);
        gather_slot<<<gblocks, 256, 0, stream>>>(h, offs, cursor, W3, b3, out, N, 2, 16);
    } else {
        edge_mlp_slot<15><<<eblocks, 256, 0, stream>>>(xb, ei, ea, W1, b1, W2, b2,
                                                       sums, cursor, h, E, N, tiles, 0);
        gather_slot<<<gblocks, 256, 0, stream>>>(h, offs, cursor, W3, b3, out, N, 0, 15);
        edge_mlp_slot<15><<<eblocks, 256, 0, stream>>>(xb, ei, ea, W1, b1, W2, b2,
                                                       sums, cursor, h, E, N, tiles, 2);
        gather_slot<<<gblocks, 256, 0, stream>>>(h, offs, cursor, W3, b3, out, N, 2, 15);
    }
}

// Round 9
// 580.100 us; speedup vs baseline: 1.0557x; 1.0557x over previous
//
#include <hip/hip_runtime.h>
#include <math.h>

#define B_SZ 4
#define IN_F 32
#define H1_F 32
#define H2_F 30
#define TPW 16   // tiles per wave (multiple of 4)

typedef unsigned int uint;
typedef unsigned short ushort;
typedef __attribute__((ext_vector_type(8))) short bf16x8;
typedef __attribute__((ext_vector_type(4))) float f32x4;
typedef __attribute__((ext_vector_type(4))) uint uint4v;   // native vec for nt-builtins

__device__ __forceinline__ float fastrcp(float x) {
#if __has_builtin(__builtin_amdgcn_rcpf)
    return __builtin_amdgcn_rcpf(x);
#else
    return 1.f / x;
#endif
}
__device__ __forceinline__ float sigmoidf_(float x) {
    return fastrcp(1.f + __expf(-x));
}
__device__ __forceinline__ ushort f2bf(float f) {
    uint u = __float_as_uint(f);
    return (ushort)((u + 0x7FFFu + ((u >> 16) & 1u)) >> 16);  // RNE
}
__device__ __forceinline__ float bf2f(ushort v) { return __uint_as_float(((uint)v) << 16); }
__device__ __forceinline__ uint pk2(float a, float b) {
    return (uint)f2bf(a) | ((uint)f2bf(b) << 16);
}

union Frag { bf16x8 v; ushort us[8]; uint u[4]; };

// ---------------------------------------------------------------------------
// fused stats (mean/sumsq of ea) + degree histogram (tgt+src combined)
// ---------------------------------------------------------------------------
__global__ void __launch_bounds__(256) stats_hist_kernel(
    const float* __restrict__ ea, const int* __restrict__ ei,
    float* __restrict__ sums, int* __restrict__ cnt, int E, int N) {
    int e = blockIdx.x * 256 + threadIdx.x;
    float a = (e < E) ? ea[e] : 0.f;
    if (e < E) {
        atomicAdd(&cnt[ei[E + e]], 1);
        atomicAdd(&cnt[ei[e]], 1);
    }
    float v = a, v2 = a * a;
    for (int off = 32; off > 0; off >>= 1) {
        v  += __shfl_down(v, off);
        v2 += __shfl_down(v2, off);
    }
    __shared__ float s1[4], s2[4];
    int wid = threadIdx.x >> 6, lane = threadIdx.x & 63;
    if (lane == 0) { s1[wid] = v; s2[wid] = v2; }
    __syncthreads();
    if (threadIdx.x == 0) {
        unsafeAtomicAdd(&sums[0], s1[0] + s1[1] + s1[2] + s1[3]);
        unsafeAtomicAdd(&sums[1], s2[0] + s2[1] + s2[2] + s2[3]);
    }
}

// ---------------------------------------------------------------------------
// x f32 [b][n][32] -> bf16 NODE-MAJOR xb [n][4][32]
// ---------------------------------------------------------------------------
__global__ void __launch_bounds__(256) xcvt_t_kernel(const float* __restrict__ x,
                                                     ushort* __restrict__ xb,
                                                     int N, long long total4) {
    long long i = (long long)blockIdx.x * 256 + threadIdx.x;
    if (i >= total4) return;
    long long row = i >> 2;
    int k = (int)(i & 3);
    int b = (int)(row / N);
    int n = (int)(row - (long long)b * N);
    const float4* p = (const float4*)(x + (((size_t)b * N + n) * IN_F) + k * 8);
    float4 v0 = p[0], v1 = p[1];
    uint4v o;
    o.x = pk2(v0.x, v0.y); o.y = pk2(v0.z, v0.w);
    o.z = pk2(v1.x, v1.y); o.w = pk2(v1.z, v1.w);
    *(uint4v*)(xb + (size_t)n * 128 + b * 32 + k * 8) = o;
}

// ---------------------------------------------------------------------------
// 3-phase multi-block exclusive scan (1024 elems/block)
// ---------------------------------------------------------------------------
__global__ void __launch_bounds__(256) scan1_kernel(const int* __restrict__ cnt,
                                                    int* __restrict__ offs,
                                                    int* __restrict__ bsum, int n) {
    __shared__ int wtot[4];
    int base = blockIdx.x * 1024 + threadIdx.x * 4;
    int4 v = {0, 0, 0, 0};
    if (base + 3 < n) v = *(const int4*)(cnt + base);
    else {
        if (base < n)     v.x = cnt[base];
        if (base + 1 < n) v.y = cnt[base + 1];
        if (base + 2 < n) v.z = cnt[base + 2];
        if (base + 3 < n) v.w = cnt[base + 3];
    }
    int s = v.x + v.y + v.z + v.w;
    int incl = s;
    int lane = threadIdx.x & 63;
    for (int d = 1; d < 64; d <<= 1) {
        int t = __shfl_up(incl, d);
        if (lane >= d) incl += t;
    }
    int wid = threadIdx.x >> 6;
    if (lane == 63) wtot[wid] = incl;
    __syncthreads();
    int woff = 0, tot = 0;
#pragma unroll
    for (int w = 0; w < 4; w++) {
        int t = wtot[w];
        if (w < wid) woff += t;
        tot += t;
    }
    int excl = woff + incl - s;
    int4 o;
    o.x = excl; o.y = excl + v.x; o.z = o.y + v.y; o.w = o.z + v.z;
    if (base + 3 < n) *(int4*)(offs + base) = o;
    else {
        if (base < n)     offs[base] = o.x;
        if (base + 1 < n) offs[base + 1] = o.y;
        if (base + 2 < n) offs[base + 2] = o.z;
        if (base + 3 < n) offs[base + 3] = o.w;
    }
    if (threadIdx.x == 0) bsum[blockIdx.x] = tot;
}

__global__ void scan2_kernel(int* __restrict__ bsum, int* __restrict__ offs,
                             int nb, int n) {
    int lane = threadIdx.x;
    if (nb <= 64) {
        int v = (lane < nb) ? bsum[lane] : 0;
        int incl = v;
        for (int d = 1; d < 64; d <<= 1) {
            int t = __shfl_up(incl, d);
            if (lane >= d) incl += t;
        }
        if (lane < nb) bsum[lane] = incl - v;
        if (lane == 63) offs[n] = incl;
    } else if (lane == 0) {
        int run = 0;
        for (int i = 0; i < nb; i++) { int t = bsum[i]; bsum[i] = run; run += t; }
        offs[n] = run;
    }
}

__global__ void __launch_bounds__(256) scan3_kernel(int* __restrict__ offs,
                                                    int* __restrict__ cursor,
                                                    const int* __restrict__ bsum, int n) {
    int base = blockIdx.x * 1024 + threadIdx.x * 4;
    int add = bsum[blockIdx.x];
    if (base + 3 < n) {
        int4 v = *(const int4*)(offs + base);
        v.x += add; v.y += add; v.z += add; v.w += add;
        *(int4*)(offs + base) = v;
        *(int4*)(cursor + base) = v;
    } else {
        for (int k = 0; k < 4; k++) {
            int i = base + k;
            if (i < n) { int v = offs[i] + add; offs[i] = v; cursor[i] = v; }
        }
    }
}

// ---------------------------------------------------------------------------
// Edge MLP (operand-swapped MFMA), two-batch pass, +/-h into padded 128-B CSR
// slots. Tile = 8 edges x 2 batches = 16 rows; row n16 = el*2 + bl.
// Slot (128 B) = [bl(2)][64 B half]; each half written by ONE uint4v nt-store
// per lane x 4 lanes = full line per instruction (no RMW, no L3 pollution).
// Memory column order per half is the q-permuted order {4q+0..3, 16+4q+0..3};
// gather compensates. Cursor atomics per group of 4 tiles, one group ahead.
// ---------------------------------------------------------------------------
__global__ void __launch_bounds__(256) edge_mlp_slot(
    const ushort* __restrict__ xb,
    const int* __restrict__ ei, const float* __restrict__ ea,
    const float* __restrict__ W1, const float* __restrict__ b1,
    const float* __restrict__ W2, const float* __restrict__ b2,
    const float* __restrict__ sums, int* __restrict__ cursor,
    ushort* __restrict__ h, int E, int N, int tiles, int boff) {
    __shared__ ushort __attribute__((aligned(16))) hbuf[4][16 * 40];
    int w = threadIdx.x >> 6;
    int lane = threadIdx.x & 63;
    int n16 = lane & 15;
    int q = lane >> 4;

    // weight fragments as operand A (= W^T)
    Frag w1f[2][2];
#pragma unroll
    for (int t = 0; t < 2; t++)
#pragma unroll
        for (int s = 0; s < 2; s++)
#pragma unroll
            for (int j = 0; j < 4; j++) {
                int k0 = 32 * s + q * 8 + 2 * j;
                w1f[t][s].u[j] = pk2(W1[(size_t)k0 * 32 + 16 * t + n16],
                                     W1[(size_t)(k0 + 1) * 32 + 16 * t + n16]);
            }
    Frag w2f[2];
#pragma unroll
    for (int t = 0; t < 2; t++) {
        int m = 16 * t + n16;
#pragma unroll
        for (int j = 0; j < 4; j++) {
            int k0 = q * 8 + 2 * j;
            float a = (m < H2_F) ? W2[(size_t)k0 * H2_F + m] : 0.f;
            float d = (m < H2_F) ? W2[(size_t)(k0 + 1) * H2_F + m] : 0.f;
            w2f[t].u[j] = pk2(a, d);
        }
    }
    float b1q[2][4], w1Lq[2][4], b2q[2][4];
#pragma unroll
    for (int t = 0; t < 2; t++)
#pragma unroll
        for (int r = 0; r < 4; r++) {
            int col = 16 * t + q * 4 + r;
            b1q[t][r]  = b1[col];
            w1Lq[t][r] = W1[(size_t)64 * 32 + col];
            b2q[t][r]  = (col < H2_F) ? b2[col] : 0.f;
        }

    float mean = sums[0] / (float)E;
    float var = (sums[1] - (float)E * mean * mean) / (float)(E - 1);
    float istd = rsqrtf(var);

    int el = n16 >> 1;            // row's edge offset within tile
    int bl = n16 & 1;             // row's batch-local
    int b  = bl + boff;
    int side = n16 & 1;           // atomic role: 0=tgt(+), 1=src(-)
    int gw = blockIdx.x * 4 + w;
    int tile0 = gw * TPW;
    if (tile0 >= tiles) return;

    // ---- group-of-4 cursor atomics: lane = tq*16 + (el*2+side) ----
    auto issue4 = [&](int gt0) -> int {
        int tt = gt0 + q;
        int eAt = tt * 8 + el;
        int slotv = 0;
        if (tt < tiles && eAt < E) {
            int node = side ? ei[eAt] : ei[E + eAt];
            slotv = atomicAdd(&cursor[node], 1);
        }
        return slotv;
    };

    // ---- 3-buffer rotating data prefetch (node-major xb: 128B per side) ----
    Frag a0b[3], a1b[3];
    float eavb[3];
    bool vrb[3];
    auto loadTile = [&](int tt, int sl) {
        Frag x0, x1;
        x0.u[0] = x0.u[1] = x0.u[2] = x0.u[3] = 0; x1 = x0;
        float ev = 0.f; bool v = false;
        if (tt < tiles) {
            int eA = tt * 8 + el;
            v = eA < E;
            int c = v ? eA : E - 1;
            int s_ = ei[c], t_ = ei[E + c];
            ev = (ea[c] - mean) * istd;
            *(uint4v*)&x0.u[0] = *(const uint4v*)(xb + (size_t)s_ * 128 + b * 32 + q * 8);
            *(uint4v*)&x1.u[0] = *(const uint4v*)(xb + (size_t)t_ * 128 + b * 32 + q * 8);
        }
        a0b[sl] = x0; a1b[sl] = x1; eavb[sl] = ev; vrb[sl] = v;
    };

    int slotCur = issue4(tile0);
    int slotNxt = 0;
    loadTile(tile0, 0);
    loadTile(tile0 + 1, 1);
    loadTile(tile0 + 2, 2);

    for (int tix = 0; tix < TPW; ++tix) {
        int tile = tile0 + tix;
        if (tile >= tiles) break;
        int p = tix & 3;
        if (p == 0 && tix + 4 < TPW) slotNxt = issue4(tile0 + tix + 4);
        int cur = tix % 3;

        float eav = eavb[cur];
        bool vrow = vrb[cur];
        f32x4 acc0, acc1;
#pragma unroll
        for (int r = 0; r < 4; r++) {
            acc0[r] = b1q[0][r] + eav * w1Lq[0][r];
            acc1[r] = b1q[1][r] + eav * w1Lq[1][r];
        }
        acc0 = __builtin_amdgcn_mfma_f32_16x16x32_bf16(w1f[0][0].v, a0b[cur].v, acc0, 0, 0, 0);
        acc0 = __builtin_amdgcn_mfma_f32_16x16x32_bf16(w1f[0][1].v, a1b[cur].v, acc0, 0, 0, 0);
        acc1 = __builtin_amdgcn_mfma_f32_16x16x32_bf16(w1f[1][0].v, a0b[cur].v, acc1, 0, 0, 0);
        acc1 = __builtin_amdgcn_mfma_f32_16x16x32_bf16(w1f[1][1].v, a1b[cur].v, acc1, 0, 0, 0);

        // buffers dead -> prefetch tile tix+3 into them
        if (tix + 3 < TPW) loadTile(tile0 + tix + 3, cur);

        uint u0 = pk2(sigmoidf_(acc0[0]), sigmoidf_(acc0[1]));
        uint u1 = pk2(sigmoidf_(acc0[2]), sigmoidf_(acc0[3]));
        uint u2 = pk2(sigmoidf_(acc1[0]), sigmoidf_(acc1[1]));
        uint u3 = pk2(sigmoidf_(acc1[2]), sigmoidf_(acc1[3]));
        uint2 p01 = {u0, u1}, p23 = {u2, u3};
        *(uint2*)&hbuf[w][n16 * 40 + q * 4]      = p01;
        *(uint2*)&hbuf[w][n16 * 40 + 16 + q * 4] = p23;

        Frag ha;
        *(uint4v*)&ha.u[0] = *(const uint4v*)&hbuf[w][n16 * 40 + q * 8];

        f32x4 c0, c1;
#pragma unroll
        for (int r = 0; r < 4; r++) { c0[r] = b2q[0][r]; c1[r] = b2q[1][r]; }
        c0 = __builtin_amdgcn_mfma_f32_16x16x32_bf16(w2f[0].v, ha.v, c0, 0, 0, 0);
        c1 = __builtin_amdgcn_mfma_f32_16x16x32_bf16(w2f[1].v, ha.v, c1, 0, 0, 0);

        // pack this lane's 8 cols {4q..4q+3, 16+4q..16+4q+3} into ONE uint4v
        uint4v tv;
        tv.x = pk2(sigmoidf_(c0[0]), sigmoidf_(c0[1]));
        tv.y = pk2(sigmoidf_(c0[2]), sigmoidf_(c0[3]));
        tv.z = pk2(sigmoidf_(c1[0]), sigmoidf_(c1[1]));
        tv.w = pk2(sigmoidf_(c1[2]), sigmoidf_(c1[3]));
        const uint SM = 0x80008000u;
        uint4v sv = tv ^ SM;

        int slot_t = __shfl(slotCur, p * 16 + el * 2);
        int slot_s = __shfl(slotCur, p * 16 + el * 2 + 1);
        if (vrow) {
            uint* bt = (uint*)h + (size_t)slot_t * 32 + bl * 16 + q * 4;
            __builtin_nontemporal_store(tv, (uint4v*)bt);
            uint* bs = (uint*)h + (size_t)slot_s * 32 + bl * 16 + q * 4;
            __builtin_nontemporal_store(sv, (uint4v*)bs);
        }
        if (p == 3) slotCur = slotNxt;
    }
}

// ---------------------------------------------------------------------------
// Gather over CONTIGUOUS 128-B slots (signs baked in), fused W3 epilogue.
// Lane jp reads uint u=jp of a slot-half; its column pair is the q-permuted
// mapping c0 = (m<2)? 4q+2m : 16+4q+2(m-2), q=jp>>2, m=jp&3.
// Lane 30 restores cursor[n]=offs[n] for the next pass.
// ---------------------------------------------------------------------------
__global__ void __launch_bounds__(256) gather_slot(
    const ushort* __restrict__ h, const int* __restrict__ offs,
    int* __restrict__ cursor,
    const float* __restrict__ W3, const float* __restrict__ b3,
    float* __restrict__ out, int N, int boff) {
    __shared__ float sW3[H2_F * 32];
    __shared__ float sb3[32];
    __shared__ float sacc[4][2][H2_F];
    for (int i = threadIdx.x; i < H2_F * 32; i += 256) sW3[i] = W3[i];
    if (threadIdx.x < 32) sb3[threadIdx.x] = b3[threadIdx.x];
    __syncthreads();

    int w = threadIdx.x >> 6, lane = threadIdx.x & 63;
    int n = blockIdx.x * 4 + w;
    if (n >= N) return;

    int s = offs[n], e = offs[n + 1];
    if (lane == 30) cursor[n] = s;
    if (lane < 30) {
        int bl = lane / 15, jp = lane % 15;
        int qq = jp >> 2, m = jp & 3;
        int c0 = (m < 2) ? (qq * 4 + 2 * m) : (16 + qq * 4 + 2 * (m - 2));
        const uint* p = (const uint*)h + (size_t)s * 32 + bl * 16 + jp;
        float a0 = 0.f, a1 = 0.f;
        int cnt = e - s;
        int i = 0;
        for (; i + 4 <= cnt; i += 4) {
            uint d0 = __builtin_nontemporal_load(p);
            uint d1 = __builtin_nontemporal_load(p + 32);
            uint d2 = __builtin_nontemporal_load(p + 64);
            uint d3 = __builtin_nontemporal_load(p + 96);
            p += 128;
            a0 += bf2f((ushort)d0) + bf2f((ushort)d1)
                + bf2f((ushort)d2) + bf2f((ushort)d3);
            a1 += bf2f((ushort)(d0 >> 16)) + bf2f((ushort)(d1 >> 16))
                + bf2f((ushort)(d2 >> 16)) + bf2f((ushort)(d3 >> 16));
        }
        for (; i < cnt; i++) {
            uint d = __builtin_nontemporal_load(p);
            p += 32;
            a0 += bf2f((ushort)d);
            a1 += bf2f((ushort)(d >> 16));
        }
        sacc[w][bl][c0]     = a0;
        sacc[w][bl][c0 + 1] = a1;
    }
    // wave-synchronous epilogue: 2 batches x 32 cols = 64 lanes
    int bl = lane >> 5, k = lane & 31;
    float o = sb3[k];
#pragma unroll
    for (int j = 0; j < H2_F; j++) o += sacc[w][bl][j] * sW3[j * 32 + k];
    out[((size_t)(boff + bl) * N + n) * 32 + k] = sigmoidf_(o);
}

// ---------------------------------------------------------------------------
extern "C" void kernel_launch(void* const* d_in, const int* in_sizes, int n_in,
                              void* d_out, int out_size, void* d_ws, size_t ws_size,
                              hipStream_t stream) {
    const float* x  = (const float*)d_in[0];
    const int*   ei = (const int*)d_in[1];
    const float* ea = (const float*)d_in[2];
    const float* W1 = (const float*)d_in[3];
    const float* b1 = (const float*)d_in[4];
    const float* W2 = (const float*)d_in[5];
    const float* b2 = (const float*)d_in[6];
    const float* W3 = (const float*)d_in[7];
    const float* b3 = (const float*)d_in[8];
    float* out = (float*)d_out;

    const int E  = in_sizes[2];
    const int N  = in_sizes[0] / (B_SZ * IN_F);
    const int BN = B_SZ * N;
    const int nb = (N + 1023) / 1024;
    const int tiles = (E + 7) / 8;
    const int waves = (tiles + TPW - 1) / TPW;
    const int eblocks = (waves + 3) / 4;

    char* base = (char*)d_ws;
    size_t misc = 0;
    int* cnt    = (int*)(base + misc); misc += (size_t)N * 4;
    float* sums = (float*)(base + misc); misc += 8;
    int* offs   = (int*)(base + misc); misc += (size_t)(N + 1) * 4;
    int* cursor = (int*)(base + misc); misc += (size_t)N * 4;
    int* bsum   = (int*)(base + misc); misc += 4096;
    misc = (misc + 255) & ~(size_t)255;
    ushort* h   = (ushort*)(base + misc);
    size_t xbOff = (misc + (size_t)2 * E * 128 + 255) & ~(size_t)255;
    ushort* xb  = (ushort*)(base + xbOff);

    hipMemsetAsync(cnt, 0, (size_t)N * 4 + 8, stream);  // cnt + sums
    stats_hist_kernel<<<(E + 255) / 256, 256, 0, stream>>>(ea, ei, sums, cnt, E, N);
    long long total4 = (long long)BN * 4;
    xcvt_t_kernel<<<(int)((total4 + 255) / 256), 256, 0, stream>>>(x, xb, N, total4);
    scan1_kernel<<<nb, 256, 0, stream>>>(cnt, offs, bsum, N);
    scan2_kernel<<<1, 64, 0, stream>>>(bsum, offs, nb, N);
    scan3_kernel<<<nb, 256, 0, stream>>>(offs, cursor, bsum, N);

    int gblocks = (N + 3) / 4;
    edge_mlp_slot<<<eblocks, 256, 0, stream>>>(xb, ei, ea, W1, b1, W2, b2,
                                               sums, cursor, h, E, N, tiles, 0);
    gather_slot<<<gblocks, 256, 0, stream>>>(h, offs, cursor, W3, b3, out, N, 0);
    edge_mlp_slot<<<eblocks, 256, 0, stream>>>(xb, ei, ea, W1, b1, W2, b2,
                                               sums, cursor, h, E, N, tiles, 2);
    gather_slot<<<gblocks, 256, 0, stream>>>(h, offs, cursor, W3, b3, out, N, 2);
}

// Round 10
// 578.881 us; speedup vs baseline: 1.0579x; 1.0021x over previous
//
#include <hip/hip_runtime.h>
#include <math.h>

#define B_SZ 4
#define IN_F 32
#define H1_F 32
#define H2_F 30
#define TPW 16   // tiles per wave (multiple of 4)

typedef unsigned int uint;
typedef unsigned short ushort;
typedef __attribute__((ext_vector_type(8))) short bf16x8;
typedef __attribute__((ext_vector_type(4))) float f32x4;
typedef __attribute__((ext_vector_type(4))) uint uint4v;

__device__ __forceinline__ float fastrcp(float x) {
#if __has_builtin(__builtin_amdgcn_rcpf)
    return __builtin_amdgcn_rcpf(x);
#else
    return 1.f / x;
#endif
}
__device__ __forceinline__ float sigmoidf_(float x) {
    return fastrcp(1.f + __expf(-x));
}
__device__ __forceinline__ ushort f2bf(float f) {
    uint u = __float_as_uint(f);
    return (ushort)((u + 0x7FFFu + ((u >> 16) & 1u)) >> 16);  // RNE
}
__device__ __forceinline__ float bf2f(ushort v) { return __uint_as_float(((uint)v) << 16); }
__device__ __forceinline__ uint pk2(float a, float b) {
    return (uint)f2bf(a) | ((uint)f2bf(b) << 16);
}

union Frag { bf16x8 v; ushort us[8]; uint u[4]; };

// ---------------------------------------------------------------------------
// fused stats (mean/sumsq of ea) + degree histogram, 16-bit PACKED counters
// ---------------------------------------------------------------------------
__global__ void __launch_bounds__(256) stats_hist_kernel(
    const float* __restrict__ ea, const int* __restrict__ ei,
    float* __restrict__ sums, uint* __restrict__ cnt16, int E, int N) {
    int e = blockIdx.x * 256 + threadIdx.x;
    float a = (e < E) ? ea[e] : 0.f;
    if (e < E) {
        int t = ei[E + e];
        int s = ei[e];
        atomicAdd(&cnt16[t >> 1], 1u << ((t & 1) * 16));
        atomicAdd(&cnt16[s >> 1], 1u << ((s & 1) * 16));
    }
    float v = a, v2 = a * a;
    for (int off = 32; off > 0; off >>= 1) {
        v  += __shfl_down(v, off);
        v2 += __shfl_down(v2, off);
    }
    __shared__ float s1[4], s2[4];
    int wid = threadIdx.x >> 6, lane = threadIdx.x & 63;
    if (lane == 0) { s1[wid] = v; s2[wid] = v2; }
    __syncthreads();
    if (threadIdx.x == 0) {
        unsafeAtomicAdd(&sums[0], s1[0] + s1[1] + s1[2] + s1[3]);
        unsafeAtomicAdd(&sums[1], s2[0] + s2[1] + s2[2] + s2[3]);
    }
}

// ---------------------------------------------------------------------------
// x f32 [b][n][32] -> bf16 NODE-MAJOR xb [n][4][32]
// ---------------------------------------------------------------------------
__global__ void __launch_bounds__(256) xcvt_t_kernel(const float* __restrict__ x,
                                                     ushort* __restrict__ xb,
                                                     int N, long long total4) {
    long long i = (long long)blockIdx.x * 256 + threadIdx.x;
    if (i >= total4) return;
    long long row = i >> 2;
    int k = (int)(i & 3);
    int b = (int)(row / N);
    int n = (int)(row - (long long)b * N);
    const float4* p = (const float4*)(x + (((size_t)b * N + n) * IN_F) + k * 8);
    float4 v0 = p[0], v1 = p[1];
    uint4v o;
    o.x = pk2(v0.x, v0.y); o.y = pk2(v0.z, v0.w);
    o.z = pk2(v1.x, v1.y); o.w = pk2(v1.z, v1.w);
    *(uint4v*)(xb + (size_t)n * 128 + b * 32 + k * 8) = o;
}

// ---------------------------------------------------------------------------
// 3-phase multi-block exclusive scan; phase 1 unpacks 16-bit counters
// ---------------------------------------------------------------------------
__global__ void __launch_bounds__(256) scan1_kernel(const uint* __restrict__ cnt16,
                                                    int* __restrict__ offs,
                                                    int* __restrict__ bsum, int n) {
    __shared__ int wtot[4];
    int base = blockIdx.x * 1024 + threadIdx.x * 4;
    int4 v = {0, 0, 0, 0};
    if (base + 3 < n) {
        uint2 wv = *(const uint2*)(cnt16 + (base >> 1));
        v.x = wv.x & 0xffff; v.y = wv.x >> 16;
        v.z = wv.y & 0xffff; v.w = wv.y >> 16;
    } else {
        int vv[4] = {0, 0, 0, 0};
        for (int k = 0; k < 4; k++) {
            int i = base + k;
            if (i < n) vv[k] = (cnt16[i >> 1] >> ((i & 1) * 16)) & 0xffff;
        }
        v.x = vv[0]; v.y = vv[1]; v.z = vv[2]; v.w = vv[3];
    }
    int s = v.x + v.y + v.z + v.w;
    int incl = s;
    int lane = threadIdx.x & 63;
    for (int d = 1; d < 64; d <<= 1) {
        int t = __shfl_up(incl, d);
        if (lane >= d) incl += t;
    }
    int wid = threadIdx.x >> 6;
    if (lane == 63) wtot[wid] = incl;
    __syncthreads();
    int woff = 0, tot = 0;
#pragma unroll
    for (int w = 0; w < 4; w++) {
        int t = wtot[w];
        if (w < wid) woff += t;
        tot += t;
    }
    int excl = woff + incl - s;
    int4 o;
    o.x = excl; o.y = excl + v.x; o.z = o.y + v.y; o.w = o.z + v.z;
    if (base + 3 < n) *(int4*)(offs + base) = o;
    else {
        if (base < n)     offs[base] = o.x;
        if (base + 1 < n) offs[base + 1] = o.y;
        if (base + 2 < n) offs[base + 2] = o.z;
        if (base + 3 < n) offs[base + 3] = o.w;
    }
    if (threadIdx.x == 0) bsum[blockIdx.x] = tot;
}

__global__ void scan2_kernel(int* __restrict__ bsum, int* __restrict__ offs,
                             int nb, int n) {
    int lane = threadIdx.x;
    if (nb <= 64) {
        int v = (lane < nb) ? bsum[lane] : 0;
        int incl = v;
        for (int d = 1; d < 64; d <<= 1) {
            int t = __shfl_up(incl, d);
            if (lane >= d) incl += t;
        }
        if (lane < nb) bsum[lane] = incl - v;
        if (lane == 63) offs[n] = incl;
    } else if (lane == 0) {
        int run = 0;
        for (int i = 0; i < nb; i++) { int t = bsum[i]; bsum[i] = run; run += t; }
        offs[n] = run;
    }
}

__global__ void __launch_bounds__(256) scan3_kernel(int* __restrict__ offs,
                                                    int* __restrict__ cursor,
                                                    const int* __restrict__ bsum, int n) {
    int base = blockIdx.x * 1024 + threadIdx.x * 4;
    int add = bsum[blockIdx.x];
    if (base + 3 < n) {
        int4 v = *(const int4*)(offs + base);
        v.x += add; v.y += add; v.z += add; v.w += add;
        *(int4*)(offs + base) = v;
        *(int4*)(cursor + base) = v;
    } else {
        for (int k = 0; k < 4; k++) {
            int i = base + k;
            if (i < n) { int v = offs[i] + add; offs[i] = v; cursor[i] = v; }
        }
    }
}

// ---------------------------------------------------------------------------
// Edge MLP (operand-swapped MFMA), two-batch pass, +/-h into padded 128-B CSR
// slots (full-line uint4v nt-stores).
// USE_SAVED=false: cursor atomics per group-of-4 tiles (pipelined); if SAVE,
//   also persists slot ids to slotT/slotS (sequential by edge).
// USE_SAVED=true: NO atomics — reads slotT/slotS saved by pass 0.
// ---------------------------------------------------------------------------
template<bool USE_SAVED, bool SAVE>
__global__ void __launch_bounds__(256) edge_mlp_slot(
    const ushort* __restrict__ xb,
    const int* __restrict__ ei, const float* __restrict__ ea,
    const float* __restrict__ W1, const float* __restrict__ b1,
    const float* __restrict__ W2, const float* __restrict__ b2,
    const float* __restrict__ sums, int* __restrict__ cursor,
    int* __restrict__ slotT, int* __restrict__ slotS,
    ushort* __restrict__ h, int E, int N, int tiles, int boff) {
    __shared__ ushort __attribute__((aligned(16))) hbuf[4][16 * 40];
    int w = threadIdx.x >> 6;
    int lane = threadIdx.x & 63;
    int n16 = lane & 15;
    int q = lane >> 4;

    Frag w1f[2][2];
#pragma unroll
    for (int t = 0; t < 2; t++)
#pragma unroll
        for (int s = 0; s < 2; s++)
#pragma unroll
            for (int j = 0; j < 4; j++) {
                int k0 = 32 * s + q * 8 + 2 * j;
                w1f[t][s].u[j] = pk2(W1[(size_t)k0 * 32 + 16 * t + n16],
                                     W1[(size_t)(k0 + 1) * 32 + 16 * t + n16]);
            }
    Frag w2f[2];
#pragma unroll
    for (int t = 0; t < 2; t++) {
        int m = 16 * t + n16;
#pragma unroll
        for (int j = 0; j < 4; j++) {
            int k0 = q * 8 + 2 * j;
            float a = (m < H2_F) ? W2[(size_t)k0 * H2_F + m] : 0.f;
            float d = (m < H2_F) ? W2[(size_t)(k0 + 1) * H2_F + m] : 0.f;
            w2f[t].u[j] = pk2(a, d);
        }
    }
    float b1q[2][4], w1Lq[2][4], b2q[2][4];
#pragma unroll
    for (int t = 0; t < 2; t++)
#pragma unroll
        for (int r = 0; r < 4; r++) {
            int col = 16 * t + q * 4 + r;
            b1q[t][r]  = b1[col];
            w1Lq[t][r] = W1[(size_t)64 * 32 + col];
            b2q[t][r]  = (col < H2_F) ? b2[col] : 0.f;
        }

    float mean = sums[0] / (float)E;
    float var = (sums[1] - (float)E * mean * mean) / (float)(E - 1);
    float istd = rsqrtf(var);

    int el = n16 >> 1;
    int bl = n16 & 1;
    int b  = bl + boff;
    int side = n16 & 1;
    int gw = blockIdx.x * 4 + w;
    int tile0 = gw * TPW;
    if (tile0 >= tiles) return;

    auto issue4 = [&](int gt0) -> int {
        int tt = gt0 + q;
        int eAt = tt * 8 + el;
        int slotv = 0;
        if (tt < tiles && eAt < E) {
            int node = side ? ei[eAt] : ei[E + eAt];
            slotv = atomicAdd(&cursor[node], 1);
            if (SAVE) {
                if (side) slotS[eAt] = slotv;
                else      slotT[eAt] = slotv;
            }
        }
        return slotv;
    };

    Frag a0b[3], a1b[3];
    float eavb[3];
    bool vrb[3];
    int sTb[3], sSb[3];
    auto loadTile = [&](int tt, int sl) {
        Frag x0, x1;
        x0.u[0] = x0.u[1] = x0.u[2] = x0.u[3] = 0; x1 = x0;
        float ev = 0.f; bool v = false;
        int sT = 0, sS = 0;
        if (tt < tiles) {
            int eA = tt * 8 + el;
            v = eA < E;
            int c = v ? eA : E - 1;
            int s_ = ei[c], t_ = ei[E + c];
            ev = (ea[c] - mean) * istd;
            *(uint4v*)&x0.u[0] = *(const uint4v*)(xb + (size_t)s_ * 128 + b * 32 + q * 8);
            *(uint4v*)&x1.u[0] = *(const uint4v*)(xb + (size_t)t_ * 128 + b * 32 + q * 8);
            if (USE_SAVED) { sT = slotT[c]; sS = slotS[c]; }
        }
        a0b[sl] = x0; a1b[sl] = x1; eavb[sl] = ev; vrb[sl] = v;
        if (USE_SAVED) { sTb[sl] = sT; sSb[sl] = sS; }
    };

    int slotCur = 0, slotNxt = 0;
    if (!USE_SAVED) slotCur = issue4(tile0);
    loadTile(tile0, 0);
    loadTile(tile0 + 1, 1);
    loadTile(tile0 + 2, 2);

    for (int tix = 0; tix < TPW; ++tix) {
        int tile = tile0 + tix;
        if (tile >= tiles) break;
        int p = tix & 3;
        if (!USE_SAVED && p == 0 && tix + 4 < TPW) slotNxt = issue4(tile0 + tix + 4);
        int cur = tix % 3;

        float eav = eavb[cur];
        bool vrow = vrb[cur];
        f32x4 acc0, acc1;
#pragma unroll
        for (int r = 0; r < 4; r++) {
            acc0[r] = b1q[0][r] + eav * w1Lq[0][r];
            acc1[r] = b1q[1][r] + eav * w1Lq[1][r];
        }
        acc0 = __builtin_amdgcn_mfma_f32_16x16x32_bf16(w1f[0][0].v, a0b[cur].v, acc0, 0, 0, 0);
        acc0 = __builtin_amdgcn_mfma_f32_16x16x32_bf16(w1f[0][1].v, a1b[cur].v, acc0, 0, 0, 0);
        acc1 = __builtin_amdgcn_mfma_f32_16x16x32_bf16(w1f[1][0].v, a0b[cur].v, acc1, 0, 0, 0);
        acc1 = __builtin_amdgcn_mfma_f32_16x16x32_bf16(w1f[1][1].v, a1b[cur].v, acc1, 0, 0, 0);

        int slot_t, slot_s;
        if (USE_SAVED) { slot_t = sTb[cur]; slot_s = sSb[cur]; }
        else {
            slot_t = __shfl(slotCur, p * 16 + el * 2);
            slot_s = __shfl(slotCur, p * 16 + el * 2 + 1);
        }

        if (tix + 3 < TPW) loadTile(tile0 + tix + 3, cur);

        uint u0 = pk2(sigmoidf_(acc0[0]), sigmoidf_(acc0[1]));
        uint u1 = pk2(sigmoidf_(acc0[2]), sigmoidf_(acc0[3]));
        uint u2 = pk2(sigmoidf_(acc1[0]), sigmoidf_(acc1[1]));
        uint u3 = pk2(sigmoidf_(acc1[2]), sigmoidf_(acc1[3]));
        uint2 p01 = {u0, u1}, p23 = {u2, u3};
        *(uint2*)&hbuf[w][n16 * 40 + q * 4]      = p01;
        *(uint2*)&hbuf[w][n16 * 40 + 16 + q * 4] = p23;

        Frag ha;
        *(uint4v*)&ha.u[0] = *(const uint4v*)&hbuf[w][n16 * 40 + q * 8];

        f32x4 c0, c1;
#pragma unroll
        for (int r = 0; r < 4; r++) { c0[r] = b2q[0][r]; c1[r] = b2q[1][r]; }
        c0 = __builtin_amdgcn_mfma_f32_16x16x32_bf16(w2f[0].v, ha.v, c0, 0, 0, 0);
        c1 = __builtin_amdgcn_mfma_f32_16x16x32_bf16(w2f[1].v, ha.v, c1, 0, 0, 0);

        uint4v tv;
        tv.x = pk2(sigmoidf_(c0[0]), sigmoidf_(c0[1]));
        tv.y = pk2(sigmoidf_(c0[2]), sigmoidf_(c0[3]));
        tv.z = pk2(sigmoidf_(c1[0]), sigmoidf_(c1[1]));
        tv.w = pk2(sigmoidf_(c1[2]), sigmoidf_(c1[3]));
        const uint SM = 0x80008000u;
        uint4v sv = tv ^ SM;

        if (vrow) {
            uint* bt = (uint*)h + (size_t)slot_t * 32 + bl * 16 + q * 4;
            __builtin_nontemporal_store(tv, (uint4v*)bt);
            uint* bs = (uint*)h + (size_t)slot_s * 32 + bl * 16 + q * 4;
            __builtin_nontemporal_store(sv, (uint4v*)bs);
        }
        if (p == 3) slotCur = slotNxt;
    }
}

// ---------------------------------------------------------------------------
// Gather over CONTIGUOUS 128-B slots, DUAL-SLOT lanes (60 active: sl=lane/30
// covers slot s+i+sl), unroll x4 => 8 slots in flight. Fused W3 epilogue.
// Lane 60 restores cursor[n]=offs[n] (for atomic-fallback pass 1).
// ---------------------------------------------------------------------------
__global__ void __launch_bounds__(256) gather_slot(
    const ushort* __restrict__ h, const int* __restrict__ offs,
    int* __restrict__ cursor,
    const float* __restrict__ W3, const float* __restrict__ b3,
    float* __restrict__ out, int N, int boff) {
    __shared__ float sW3[H2_F * 32];
    __shared__ float sb3[32];
    __shared__ float sacc[4][2][H2_F];
    for (int i = threadIdx.x; i < H2_F * 32; i += 256) sW3[i] = W3[i];
    if (threadIdx.x < 32) sb3[threadIdx.x] = b3[threadIdx.x];
    __syncthreads();

    int w = threadIdx.x >> 6, lane = threadIdx.x & 63;
    int n = blockIdx.x * 4 + w;
    if (n >= N) return;

    int s = offs[n], e = offs[n + 1];
    if (lane == 60) cursor[n] = s;

    float a0 = 0.f, a1 = 0.f;
    int bl = 0, c0i = 0;
    if (lane < 60) {
        int sl = lane >= 30 ? 1 : 0;
        int r = lane - sl * 30;
        bl = r / 15;
        int jp = r % 15;
        int qq = jp >> 2, m = jp & 3;
        c0i = (m < 2) ? (qq * 4 + 2 * m) : (16 + qq * 4 + 2 * (m - 2));
        int cnt = e - s;
        const uint* p = (const uint*)h + (size_t)(s + sl) * 32 + bl * 16 + jp;
        int i = 0;
        for (; i + 8 <= cnt; i += 8) {
            uint d0 = __builtin_nontemporal_load(p);
            uint d1 = __builtin_nontemporal_load(p + 64);
            uint d2 = __builtin_nontemporal_load(p + 128);
            uint d3 = __builtin_nontemporal_load(p + 192);
            p += 256;
            a0 += bf2f((ushort)d0) + bf2f((ushort)d1)
                + bf2f((ushort)d2) + bf2f((ushort)d3);
            a1 += bf2f((ushort)(d0 >> 16)) + bf2f((ushort)(d1 >> 16))
                + bf2f((ushort)(d2 >> 16)) + bf2f((ushort)(d3 >> 16));
        }
        for (; i + 2 <= cnt; i += 2) {
            uint d = __builtin_nontemporal_load(p);
            p += 64;
            a0 += bf2f((ushort)d);
            a1 += bf2f((ushort)(d >> 16));
        }
        if (sl == 0 && i < cnt) {
            uint d = __builtin_nontemporal_load(p);
            a0 += bf2f((ushort)d);
            a1 += bf2f((ushort)(d >> 16));
        }
    }
    // combine the two slot-halves (lane<30 += lane+30) and publish
    float u0 = __shfl(a0, lane + 30);
    float u1 = __shfl(a1, lane + 30);
    if (lane < 30) {
        sacc[w][bl][c0i]     = a0 + u0;
        sacc[w][bl][c0i + 1] = a1 + u1;
    }
    // wave-synchronous epilogue: 2 batches x 32 cols = 64 lanes
    int bl2 = lane >> 5, k = lane & 31;
    float o = sb3[k];
#pragma unroll
    for (int j = 0; j < H2_F; j++) o += sacc[w][bl2][j] * sW3[j * 32 + k];
    out[((size_t)(boff + bl2) * N + n) * 32 + k] = sigmoidf_(o);
}

// ---------------------------------------------------------------------------
extern "C" void kernel_launch(void* const* d_in, const int* in_sizes, int n_in,
                              void* d_out, int out_size, void* d_ws, size_t ws_size,
                              hipStream_t stream) {
    const float* x  = (const float*)d_in[0];
    const int*   ei = (const int*)d_in[1];
    const float* ea = (const float*)d_in[2];
    const float* W1 = (const float*)d_in[3];
    const float* b1 = (const float*)d_in[4];
    const float* W2 = (const float*)d_in[5];
    const float* b2 = (const float*)d_in[6];
    const float* W3 = (const float*)d_in[7];
    const float* b3 = (const float*)d_in[8];
    float* out = (float*)d_out;

    const int E  = in_sizes[2];
    const int N  = in_sizes[0] / (B_SZ * IN_F);
    const int BN = B_SZ * N;
    const int nb = (N + 1023) / 1024;
    const int tiles = (E + 7) / 8;
    const int waves = (tiles + TPW - 1) / TPW;
    const int eblocks = (waves + 3) / 4;

    char* base = (char*)d_ws;
    size_t cnt16Bytes = ((size_t)N / 2 + 2) * 4;
    size_t misc = 0;
    uint* cnt16  = (uint*)(base + misc); misc += cnt16Bytes;
    float* sums  = (float*)(base + misc); misc += 8;
    int* offs    = (int*)(base + misc); misc += (size_t)(N + 1) * 4;
    int* cursor  = (int*)(base + misc); misc += (size_t)N * 4;
    int* bsum    = (int*)(base + misc); misc += 4096;
    size_t miscNoSlots = misc;
    int* slotT   = (int*)(base + misc); misc += (size_t)E * 4;
    int* slotS   = (int*)(base + misc); misc += (size_t)E * 4;

    size_t hOff  = (misc + 255) & ~(size_t)255;
    size_t xbOff = (hOff + (size_t)2 * E * 128 + 255) & ~(size_t)255;
    size_t needWithSlots = xbOff + (size_t)BN * IN_F * 2;

    bool haveSlots = (ws_size >= needWithSlots);
    if (!haveSlots) {  // compact layout: no slot arrays
        hOff  = (miscNoSlots + 255) & ~(size_t)255;
        xbOff = (hOff + (size_t)2 * E * 128 + 255) & ~(size_t)255;
        slotT = slotS = nullptr;
    }
    ushort* h  = (ushort*)(base + hOff);
    ushort* xb = (ushort*)(base + xbOff);

    hipMemsetAsync(base, 0, cnt16Bytes + 8, stream);  // cnt16 + sums
    stats_hist_kernel<<<(E + 255) / 256, 256, 0, stream>>>(ea, ei, sums, cnt16, E, N);
    long long total4 = (long long)BN * 4;
    xcvt_t_kernel<<<(int)((total4 + 255) / 256), 256, 0, stream>>>(x, xb, N, total4);
    scan1_kernel<<<nb, 256, 0, stream>>>(cnt16, offs, bsum, N);
    scan2_kernel<<<1, 64, 0, stream>>>(bsum, offs, nb, N);
    scan3_kernel<<<nb, 256, 0, stream>>>(offs, cursor, bsum, N);

    int gblocks = (N + 3) / 4;
    if (haveSlots) {
        edge_mlp_slot<false, true><<<eblocks, 256, 0, stream>>>(
            xb, ei, ea, W1, b1, W2, b2, sums, cursor, slotT, slotS, h, E, N, tiles, 0);
        gather_slot<<<gblocks, 256, 0, stream>>>(h, offs, cursor, W3, b3, out, N, 0);
        edge_mlp_slot<true, false><<<eblocks, 256, 0, stream>>>(
            xb, ei, ea, W1, b1, W2, b2, sums, cursor, slotT, slotS, h, E, N, tiles, 2);
        gather_slot<<<gblocks, 256, 0, stream>>>(h, offs, cursor, W3, b3, out, N, 2);
    } else {
        edge_mlp_slot<false, false><<<eblocks, 256, 0, stream>>>(
            xb, ei, ea, W1, b1, W2, b2, sums, cursor, slotT, slotS, h, E, N, tiles, 0);
        gather_slot<<<gblocks, 256, 0, stream>>>(h, offs, cursor, W3, b3, out, N, 0);
        edge_mlp_slot<false, false><<<eblocks, 256, 0, stream>>>(
            xb, ei, ea, W1, b1, W2, b2, sums, cursor, slotT, slotS, h, E, N, tiles, 2);
        gather_slot<<<gblocks, 256, 0, stream>>>(h, offs, cursor, W3, b3, out, N, 2);
    }
}